// Round 1
// 1877.023 us; speedup vs baseline: 1.1013x; 1.1013x over previous
//
#include <hip/hip_runtime.h>
#include <math.h>

#define F0 1433
#define F1 32
#define F2 7

// ---------------- degree / dinv ----------------
__global__ void k_init_deg(float* __restrict__ deg, int N) {
    int i = blockIdx.x * 256 + threadIdx.x;
    if (i < N) deg[i] = 1.0f;   // self-loop contributes 1
}

__global__ void k_count_deg(const int* __restrict__ dst, float* __restrict__ deg, int E) {
    int e = blockIdx.x * 256 + threadIdx.x;
    if (e < E) atomicAdd(&deg[dst[e]], 1.0f);
}

__global__ void k_dinv(float* __restrict__ deg, int N) {
    int i = blockIdx.x * 256 + threadIdx.x;
    if (i < N) deg[i] = rsqrtf(deg[i]);   // deg >= 1 always (self-loops)
}

// ---------------- GEMM1: h1[N,32] = x[N,1433] @ W1[1433,32] ----------------
// BM=128 rows/block, BK=64 K-chunk, 256 threads.
// Thread tile: 4 rows (r, r+32, r+64, r+96) x 4 cols -> 8 FMA per ds_read_b128.
// Register-prefetch double buffering: next tile loaded global->reg during compute,
// written to LDS after the post-compute barrier (hides ~900cy HBM latency).
// LDS row stride 68 (272 B, 16B-aligned): wave's 8 row-groups hit banks [4r,4r+3]
// -> all 32 banks, 8-way broadcast, conflict-free. Epilogue also writes
// agg1 = h1*dinv^2 (fuses the old k_selfloop1).
#define BM 128
#define BK 64
#define XS_LD 68

#define STAGE_LOAD(K0)                                                       \
    {                                                                        \
        const int gk = (K0) + j;                                             \
        const bool kok = gk < F0;                                            \
        const float* xp = x + (long)(row0 + i0) * F0 + gk;                   \
        if (rowfull) {                                                       \
            _Pragma("unroll")                                                \
            for (int l = 0; l < 32; ++l)                                     \
                px[l] = kok ? xp[(long)(4 * l) * F0] : 0.f;                  \
        } else {                                                             \
            _Pragma("unroll")                                                \
            for (int l = 0; l < 32; ++l) {                                   \
                int gr = row0 + i0 + 4 * l;                                  \
                px[l] = (gr < N && kok) ? xp[(long)(4 * l) * F0] : 0.f;      \
            }                                                                \
        }                                                                    \
        _Pragma("unroll")                                                    \
        for (int l = 0; l < 8; ++l) {                                        \
            int idx = tid + l * 256;                                         \
            int gkw = (K0) + (idx >> 5);                                     \
            pw[l] = (gkw < F0) ? W[gkw * F1 + (idx & 31)] : 0.f;             \
        }                                                                    \
    }

#define STAGE_WRITE()                                                        \
    {                                                                        \
        _Pragma("unroll")                                                    \
        for (int l = 0; l < 32; ++l) xs[(i0 + 4 * l) * XS_LD + j] = px[l];   \
        _Pragma("unroll")                                                    \
        for (int l = 0; l < 8; ++l) wsm[tid + l * 256] = pw[l];              \
    }

#define COMPUTE()                                                            \
    _Pragma("unroll")                                                        \
    for (int kk = 0; kk < BK; kk += 4) {                                     \
        float4 x0 = *(const float4*)&xs[(r     ) * XS_LD + kk];              \
        float4 x1 = *(const float4*)&xs[(r + 32) * XS_LD + kk];              \
        float4 x2 = *(const float4*)&xs[(r + 64) * XS_LD + kk];              \
        float4 x3 = *(const float4*)&xs[(r + 96) * XS_LD + kk];              \
        const float a0[4] = {x0.x, x0.y, x0.z, x0.w};                        \
        const float a1[4] = {x1.x, x1.y, x1.z, x1.w};                        \
        const float a2[4] = {x2.x, x2.y, x2.z, x2.w};                        \
        const float a3[4] = {x3.x, x3.y, x3.z, x3.w};                        \
        _Pragma("unroll")                                                    \
        for (int u = 0; u < 4; ++u) {                                        \
            float4 w = *(const float4*)&wsm[(kk + u) * F1 + cg * 4];         \
            acc[0][0] += a0[u] * w.x; acc[0][1] += a0[u] * w.y;              \
            acc[0][2] += a0[u] * w.z; acc[0][3] += a0[u] * w.w;              \
            acc[1][0] += a1[u] * w.x; acc[1][1] += a1[u] * w.y;              \
            acc[1][2] += a1[u] * w.z; acc[1][3] += a1[u] * w.w;              \
            acc[2][0] += a2[u] * w.x; acc[2][1] += a2[u] * w.y;              \
            acc[2][2] += a2[u] * w.z; acc[2][3] += a2[u] * w.w;              \
            acc[3][0] += a3[u] * w.x; acc[3][1] += a3[u] * w.y;              \
            acc[3][2] += a3[u] * w.z; acc[3][3] += a3[u] * w.w;              \
        }                                                                    \
    }

__global__ __launch_bounds__(256, 3) void k_gemm1(const float* __restrict__ x,
                                                  const float* __restrict__ W,
                                                  const float* __restrict__ dinv,
                                                  float* __restrict__ h,
                                                  float* __restrict__ agg, int N) {
    __shared__ float xs[BM * XS_LD];   // 34816 B
    __shared__ float wsm[BK * F1];     // 8192 B  -> 43008 B total, 3 blocks/CU
    const int tid  = threadIdx.x;
    const int row0 = blockIdx.x * BM;
    const int cg   = tid & 7;    // col group: cols cg*4 .. cg*4+3
    const int r    = tid >> 3;   // 0..31 -> rows r, r+32, r+64, r+96
    const int j    = tid & 63;   // x-staging column (constant per thread)
    const int i0   = tid >> 6;   // x-staging base row (0..3), rows i0+4l
    const bool rowfull = (row0 + BM <= N);

    float acc[4][4] = {{0.f, 0.f, 0.f, 0.f}, {0.f, 0.f, 0.f, 0.f},
                       {0.f, 0.f, 0.f, 0.f}, {0.f, 0.f, 0.f, 0.f}};
    float px[32];
    float pw[8];

    STAGE_LOAD(0)
    STAGE_WRITE()
    __syncthreads();

    const int nt = (F0 + BK - 1) / BK;   // 23
    for (int t = 0; t < nt - 1; ++t) {
        STAGE_LOAD((t + 1) * BK)     // issue next-tile loads (overlap with compute)
        COMPUTE()
        __syncthreads();             // everyone done reading current tile
        STAGE_WRITE()                // vmcnt drains here, latency already hidden
        __syncthreads();
    }
    COMPUTE()

    #pragma unroll
    for (int m = 0; m < 4; ++m) {
        int gr = row0 + r + 32 * m;
        if (gr < N) {
            float4 o = make_float4(acc[m][0], acc[m][1], acc[m][2], acc[m][3]);
            *(float4*)&h[(long)gr * F1 + cg * 4] = o;
            float d = dinv[gr];
            float dd = d * d;
            *(float4*)&agg[(long)gr * F1 + cg * 4] =
                make_float4(o.x * dd, o.y * dd, o.z * dd, o.w * dd);
        }
    }
}

// ---------------- layer-1 aggregation ----------------
// one thread per (edge, feature); 2 edges per wave
__global__ void k_scatter1(const int* __restrict__ src, const int* __restrict__ dst,
                           const float* __restrict__ dinv, const float* __restrict__ h1,
                           float* __restrict__ agg, int E) {
    int t = blockIdx.x * 256 + threadIdx.x;
    int e = t >> 5;
    if (e >= E) return;
    int f = t & 31;
    int s = src[e], d = dst[e];
    float w = dinv[s] * dinv[d];
    atomicAdd(&agg[d * F1 + f], h1[s * F1 + f] * w);
}

// ---------------- fused: ReLU(agg1+b1) @ W2 -> h2 ; out init = h2*dinv^2 ----------------
__global__ __launch_bounds__(256) void k_layer2(const float* __restrict__ agg1,
                                                const float* __restrict__ b1,
                                                const float* __restrict__ W2,
                                                const float* __restrict__ dinv,
                                                float* __restrict__ h2,
                                                float* __restrict__ out, int N) {
    __shared__ float w2s[F1 * F2];
    __shared__ float b1s[F1];
    int tid = threadIdx.x;
    if (tid < F1 * F2) w2s[tid] = W2[tid];
    if (tid < F1) b1s[tid] = b1[tid];
    __syncthreads();
    int i = blockIdx.x * 256 + tid;
    if (i >= N) return;
    float v[F1];
    #pragma unroll
    for (int u = 0; u < 8; ++u) {
        float4 t = *(const float4*)&agg1[(long)i * F1 + u * 4];
        v[u*4+0] = fmaxf(t.x + b1s[u*4+0], 0.f);
        v[u*4+1] = fmaxf(t.y + b1s[u*4+1], 0.f);
        v[u*4+2] = fmaxf(t.z + b1s[u*4+2], 0.f);
        v[u*4+3] = fmaxf(t.w + b1s[u*4+3], 0.f);
    }
    float o[F2] = {0.f, 0.f, 0.f, 0.f, 0.f, 0.f, 0.f};
    #pragma unroll
    for (int k = 0; k < F1; ++k) {
        float a = v[k];
        #pragma unroll
        for (int c = 0; c < F2; ++c) o[c] += a * w2s[k * F2 + c];
    }
    float di = dinv[i];
    float dd = di * di;
    #pragma unroll
    for (int c = 0; c < F2; ++c) {
        h2[(long)i * F2 + c] = o[c];
        out[(long)i * F2 + c] = o[c] * dd;
    }
}

// one thread per (edge, class); 8 lanes/edge (lane 7 idle)
__global__ void k_scatter2(const int* __restrict__ src, const int* __restrict__ dst,
                           const float* __restrict__ dinv, const float* __restrict__ h2,
                           float* __restrict__ out, int E) {
    int t = blockIdx.x * 256 + threadIdx.x;
    int e = t >> 3;
    int c = t & 7;
    if (e >= E || c >= F2) return;
    int s = src[e], d = dst[e];
    float w = dinv[s] * dinv[d];
    atomicAdd(&out[(long)d * F2 + c], h2[(long)s * F2 + c] * w);
}

// ---------------- +b2 then log_softmax, in place ----------------
__global__ void k_logsoftmax(float* __restrict__ out, const float* __restrict__ b2, int N) {
    int i = blockIdx.x * 256 + threadIdx.x;
    if (i >= N) return;
    float v[F2];
    float m = -1e30f;
    #pragma unroll
    for (int c = 0; c < F2; ++c) {
        v[c] = out[(long)i * F2 + c] + b2[c];
        m = fmaxf(m, v[c]);
    }
    float s = 0.f;
    #pragma unroll
    for (int c = 0; c < F2; ++c) s += expf(v[c] - m);
    float l = logf(s);
    #pragma unroll
    for (int c = 0; c < F2; ++c) out[(long)i * F2 + c] = v[c] - m - l;
}

extern "C" void kernel_launch(void* const* d_in, const int* in_sizes, int n_in,
                              void* d_out, int out_size, void* d_ws, size_t ws_size,
                              hipStream_t stream) {
    const float* x  = (const float*)d_in[0];
    const int*   ei = (const int*)d_in[1];
    const float* W1 = (const float*)d_in[2];
    const float* b1 = (const float*)d_in[3];
    const float* W2 = (const float*)d_in[4];
    const float* b2 = (const float*)d_in[5];
    float* out = (float*)d_out;

    const int N = in_sizes[0] / F0;      // 100000
    const int E = in_sizes[1] / 2;       // 3200000
    const int* src = ei;
    const int* dst = ei + E;

    // workspace layout (floats): dinv[N] | h1[N*32] (aliased by h2[N*7]) | agg1[N*32]
    float* ws   = (float*)d_ws;
    size_t o    = 0;
    float* dinv = ws;        o += (size_t)((N + 3) & ~3);
    float* h1   = ws + o;    o += (size_t)N * F1;
    float* agg1 = ws + o;    o += (size_t)N * F1;
    float* h2   = h1;        // h1 is dead after k_scatter1

    const int nb_N  = (N + 255) / 256;
    const int nb_E  = (E + 255) / 256;

    k_init_deg  <<<nb_N, 256, 0, stream>>>(dinv, N);
    k_count_deg <<<nb_E, 256, 0, stream>>>(dst, dinv, E);
    k_dinv      <<<nb_N, 256, 0, stream>>>(dinv, N);

    k_gemm1     <<<(N + BM - 1) / BM, 256, 0, stream>>>(x, W1, dinv, h1, agg1, N);

    k_scatter1  <<<((size_t)E * 32 + 255) / 256, 256, 0, stream>>>(src, dst, dinv, h1, agg1, E);

    k_layer2    <<<nb_N, 256, 0, stream>>>(agg1, b1, W2, dinv, h2, out, N);

    k_scatter2  <<<((size_t)E * 8 + 255) / 256, 256, 0, stream>>>(src, dst, dinv, h2, out, E);

    k_logsoftmax<<<nb_N, 256, 0, stream>>>(out, b2, N);
}

// Round 2
// 1669.369 us; speedup vs baseline: 1.2383x; 1.1244x over previous
//
#include <hip/hip_runtime.h>
#include <math.h>

#define F0 1433
#define F1 32
#define F2 7

// ---------------- degree / dinv ----------------
__global__ void k_init_deg(float* __restrict__ deg, int N) {
    int i = blockIdx.x * 256 + threadIdx.x;
    if (i < N) deg[i] = 1.0f;   // self-loop contributes 1
}

__global__ void k_count_deg(const int* __restrict__ dst, float* __restrict__ deg, int E) {
    int e = blockIdx.x * 256 + threadIdx.x;
    if (e < E) atomicAdd(&deg[dst[e]], 1.0f);
}

__global__ void k_dinv(float* __restrict__ deg, int N) {
    int i = blockIdx.x * 256 + threadIdx.x;
    if (i < N) deg[i] = rsqrtf(deg[i]);   // deg >= 1 always (self-loops)
}

// ---------------- GEMM1: h1[N,32] = x[N,1433] @ W1[1433,32] ----------------
// BM=128 rows/block, BK=64, 256 threads, thread tile 4 rows x 4 cols.
// Staging via __builtin_amdgcn_global_load_lds (async DMA, zero staging VGPRs ->
// no scratch spill). LDS dest is linear (wave-uniform base + lane*4), so bank
// spreading is done by swizzling the GLOBAL source address at float4 granularity
// (slot group g_phys = g ^ (row&7)); the ds_read side applies the same XOR.
// Read banks: 4*((g ^ (r&7)) mod 8) -> 8 distinct quads per wave, conflict-free.
// 22 full K-tiles via DMA; K-tail (25 cols) register-staged with predication.
// Epilogue also writes agg1 = h1*dinv^2 (fused self-loop term).
#define BM 128
#define BK 64
#define NT_FULL 22
#define KTAIL 1408

typedef const __attribute__((address_space(1))) void* gas_ptr;
typedef __attribute__((address_space(3))) void* las_ptr;

__device__ __forceinline__ void gl_lds4(const void* g, void* l) {
    __builtin_amdgcn_global_load_lds((gas_ptr)g, (las_ptr)l, 4, 0, 0);
}

#define COMPUTE()                                                            \
    _Pragma("unroll")                                                        \
    for (int kk = 0; kk < BK; kk += 4) {                                     \
        const int xo = (((kk >> 2) ^ key) << 2);                             \
        float4 x0 = *(const float4*)&xs[(r     ) * BK + xo];                 \
        float4 x1 = *(const float4*)&xs[(r + 32) * BK + xo];                 \
        float4 x2 = *(const float4*)&xs[(r + 64) * BK + xo];                 \
        float4 x3 = *(const float4*)&xs[(r + 96) * BK + xo];                 \
        const float a0[4] = {x0.x, x0.y, x0.z, x0.w};                        \
        const float a1[4] = {x1.x, x1.y, x1.z, x1.w};                        \
        const float a2[4] = {x2.x, x2.y, x2.z, x2.w};                        \
        const float a3[4] = {x3.x, x3.y, x3.z, x3.w};                        \
        _Pragma("unroll")                                                    \
        for (int u = 0; u < 4; ++u) {                                        \
            float4 w = *(const float4*)&wsm[(kk + u) * F1 + cg * 4];         \
            acc[0][0] += a0[u] * w.x; acc[0][1] += a0[u] * w.y;              \
            acc[0][2] += a0[u] * w.z; acc[0][3] += a0[u] * w.w;              \
            acc[1][0] += a1[u] * w.x; acc[1][1] += a1[u] * w.y;              \
            acc[1][2] += a1[u] * w.z; acc[1][3] += a1[u] * w.w;              \
            acc[2][0] += a2[u] * w.x; acc[2][1] += a2[u] * w.y;              \
            acc[2][2] += a2[u] * w.z; acc[2][3] += a2[u] * w.w;              \
            acc[3][0] += a3[u] * w.x; acc[3][1] += a3[u] * w.y;              \
            acc[3][2] += a3[u] * w.z; acc[3][3] += a3[u] * w.w;              \
        }                                                                    \
    }

__global__ __launch_bounds__(256) void k_gemm1(const float* __restrict__ x,
                                               const float* __restrict__ W,
                                               const float* __restrict__ dinv,
                                               float* __restrict__ h,
                                               float* __restrict__ agg, int N) {
    __shared__ float xs[BM * BK];     // 32768 B, source-swizzled layout
    __shared__ float wsm[BK * F1];    // 8192 B (linear)
    const int tid  = threadIdx.x;
    const int lane = tid & 63;
    const int wv   = tid >> 6;        // wave id 0..3
    const int row0 = blockIdx.x * BM;
    const int cg   = tid & 7;         // col group: cols cg*4..cg*4+3
    const int r    = tid >> 3;        // 0..31 -> rows r, r+32, r+64, r+96
    const int key  = r & 7;
    const bool rowfull = (row0 + BM <= N);

    // per-lane swizzled within-tile k offsets, one per row-key
    int lo[8];
    #pragma unroll
    for (int q = 0; q < 8; ++q)
        lo[q] = (((lane >> 2) ^ q) << 2) | (lane & 3);

    float acc[4][4] = {{0.f, 0.f, 0.f, 0.f}, {0.f, 0.f, 0.f, 0.f},
                       {0.f, 0.f, 0.f, 0.f}, {0.f, 0.f, 0.f, 0.f}};

    for (int t = 0; t < NT_FULL; ++t) {
        const int k0 = t * BK;
        __syncthreads();   // previous tile's reads complete before DMA overwrite
        // ---- async stage x: wave wv owns rows wv*32 .. wv*32+31 ----
        if (rowfull) {
            const float* xb = x + (size_t)(row0 + wv * 32) * F0 + k0;
            #pragma unroll
            for (int it = 0; it < 32; ++it)
                gl_lds4(xb + (size_t)it * F0 + lo[it & 7],
                        xs + (wv * 32 + it) * BK);
        } else {
            #pragma unroll
            for (int it = 0; it < 32; ++it) {
                int gr = row0 + wv * 32 + it;
                if (gr > N - 1) gr = N - 1;   // clamp: safe read, store guarded
                gl_lds4(x + (size_t)gr * F0 + k0 + lo[it & 7],
                        xs + (wv * 32 + it) * BK);
            }
        }
        // ---- async stage W (contiguous, linear) ----
        {
            const float* wb = W + (size_t)k0 * F1 + wv * 512 + lane;
            #pragma unroll
            for (int it = 0; it < 8; ++it)
                gl_lds4(wb + it * 64, wsm + wv * 512 + it * 64);
        }
        __syncthreads();   // vmcnt drains here: tile visible to all waves
        COMPUTE();
    }

    // ---- K tail: 25 valid cols, register-staged + predicated ----
    __syncthreads();
    {
        const int j = lane;
        const int i0 = wv;
        #pragma unroll
        for (int l = 0; l < 32; ++l) {
            int row = i0 + 4 * l;
            int gr = row0 + row;
            int gk = KTAIL + j;
            float v = (gr < N && gk < F0) ? x[(size_t)gr * F0 + gk] : 0.f;
            xs[row * BK + ((((j >> 2) ^ (row & 7)) << 2) | (j & 3))] = v;
        }
        #pragma unroll
        for (int l = 0; l < 8; ++l) {
            int idx = tid + l * 256;
            int gk = KTAIL + (idx >> 5);
            wsm[idx] = (gk < F0) ? W[gk * F1 + (idx & 31)] : 0.f;
        }
    }
    __syncthreads();
    COMPUTE();

    #pragma unroll
    for (int m = 0; m < 4; ++m) {
        int gr = row0 + r + 32 * m;
        if (gr < N) {
            float4 o = make_float4(acc[m][0], acc[m][1], acc[m][2], acc[m][3]);
            *(float4*)&h[(size_t)gr * F1 + cg * 4] = o;
            float d = dinv[gr];
            float dd = d * d;
            *(float4*)&agg[(size_t)gr * F1 + cg * 4] =
                make_float4(o.x * dd, o.y * dd, o.z * dd, o.w * dd);
        }
    }
}

// ---------------- layer-1 aggregation ----------------
// one thread per (edge, feature); 2 edges per wave
__global__ void k_scatter1(const int* __restrict__ src, const int* __restrict__ dst,
                           const float* __restrict__ dinv, const float* __restrict__ h1,
                           float* __restrict__ agg, int E) {
    int t = blockIdx.x * 256 + threadIdx.x;
    int e = t >> 5;
    if (e >= E) return;
    int f = t & 31;
    int s = src[e], d = dst[e];
    float w = dinv[s] * dinv[d];
    atomicAdd(&agg[d * F1 + f], h1[s * F1 + f] * w);
}

// ---------------- fused: ReLU(agg1+b1) @ W2 -> h2 ; out init = h2*dinv^2 ----------------
__global__ __launch_bounds__(256) void k_layer2(const float* __restrict__ agg1,
                                                const float* __restrict__ b1,
                                                const float* __restrict__ W2,
                                                const float* __restrict__ dinv,
                                                float* __restrict__ h2,
                                                float* __restrict__ out, int N) {
    __shared__ float w2s[F1 * F2];
    __shared__ float b1s[F1];
    int tid = threadIdx.x;
    if (tid < F1 * F2) w2s[tid] = W2[tid];
    if (tid < F1) b1s[tid] = b1[tid];
    __syncthreads();
    int i = blockIdx.x * 256 + tid;
    if (i >= N) return;
    float v[F1];
    #pragma unroll
    for (int u = 0; u < 8; ++u) {
        float4 t = *(const float4*)&agg1[(long)i * F1 + u * 4];
        v[u*4+0] = fmaxf(t.x + b1s[u*4+0], 0.f);
        v[u*4+1] = fmaxf(t.y + b1s[u*4+1], 0.f);
        v[u*4+2] = fmaxf(t.z + b1s[u*4+2], 0.f);
        v[u*4+3] = fmaxf(t.w + b1s[u*4+3], 0.f);
    }
    float o[F2] = {0.f, 0.f, 0.f, 0.f, 0.f, 0.f, 0.f};
    #pragma unroll
    for (int k = 0; k < F1; ++k) {
        float a = v[k];
        #pragma unroll
        for (int c = 0; c < F2; ++c) o[c] += a * w2s[k * F2 + c];
    }
    float di = dinv[i];
    float dd = di * di;
    #pragma unroll
    for (int c = 0; c < F2; ++c) {
        h2[(long)i * F2 + c] = o[c];
        out[(long)i * F2 + c] = o[c] * dd;
    }
}

// one thread per (edge, class); 8 lanes/edge (lane 7 idle)
__global__ void k_scatter2(const int* __restrict__ src, const int* __restrict__ dst,
                           const float* __restrict__ dinv, const float* __restrict__ h2,
                           float* __restrict__ out, int E) {
    int t = blockIdx.x * 256 + threadIdx.x;
    int e = t >> 3;
    int c = t & 7;
    if (e >= E || c >= F2) return;
    int s = src[e], d = dst[e];
    float w = dinv[s] * dinv[d];
    atomicAdd(&out[(long)d * F2 + c], h2[(long)s * F2 + c] * w);
}

// ---------------- +b2 then log_softmax, in place ----------------
__global__ void k_logsoftmax(float* __restrict__ out, const float* __restrict__ b2, int N) {
    int i = blockIdx.x * 256 + threadIdx.x;
    if (i >= N) return;
    float v[F2];
    float m = -1e30f;
    #pragma unroll
    for (int c = 0; c < F2; ++c) {
        v[c] = out[(long)i * F2 + c] + b2[c];
        m = fmaxf(m, v[c]);
    }
    float s = 0.f;
    #pragma unroll
    for (int c = 0; c < F2; ++c) s += expf(v[c] - m);
    float l = logf(s);
    #pragma unroll
    for (int c = 0; c < F2; ++c) out[(long)i * F2 + c] = v[c] - m - l;
}

extern "C" void kernel_launch(void* const* d_in, const int* in_sizes, int n_in,
                              void* d_out, int out_size, void* d_ws, size_t ws_size,
                              hipStream_t stream) {
    const float* x  = (const float*)d_in[0];
    const int*   ei = (const int*)d_in[1];
    const float* W1 = (const float*)d_in[2];
    const float* b1 = (const float*)d_in[3];
    const float* W2 = (const float*)d_in[4];
    const float* b2 = (const float*)d_in[5];
    float* out = (float*)d_out;

    const int N = in_sizes[0] / F0;      // 100000
    const int E = in_sizes[1] / 2;       // 3200000
    const int* src = ei;
    const int* dst = ei + E;

    // workspace layout (floats): dinv[N] | h1[N*32] (aliased by h2[N*7]) | agg1[N*32]
    float* ws   = (float*)d_ws;
    size_t o    = 0;
    float* dinv = ws;        o += (size_t)((N + 3) & ~3);
    float* h1   = ws + o;    o += (size_t)N * F1;
    float* agg1 = ws + o;    o += (size_t)N * F1;
    float* h2   = h1;        // h1 is dead after k_scatter1

    const int nb_N  = (N + 255) / 256;
    const int nb_E  = (E + 255) / 256;

    k_init_deg  <<<nb_N, 256, 0, stream>>>(dinv, N);
    k_count_deg <<<nb_E, 256, 0, stream>>>(dst, dinv, E);
    k_dinv      <<<nb_N, 256, 0, stream>>>(dinv, N);

    k_gemm1     <<<(N + BM - 1) / BM, 256, 0, stream>>>(x, W1, dinv, h1, agg1, N);

    k_scatter1  <<<((size_t)E * 32 + 255) / 256, 256, 0, stream>>>(src, dst, dinv, h1, agg1, E);

    k_layer2    <<<nb_N, 256, 0, stream>>>(agg1, b1, W2, dinv, h2, out, N);

    k_scatter2  <<<((size_t)E * 8 + 255) / 256, 256, 0, stream>>>(src, dst, dinv, h2, out, E);

    k_logsoftmax<<<nb_N, 256, 0, stream>>>(out, b2, N);
}